// Round 11
// baseline (174.769 us; speedup 1.0000x reference)
//
#include <hip/hip_runtime.h>
#include <stdint.h>
#include <string.h>

#define NS 4096
#define DIM 2048
#define MARGINF 0.3f

typedef __bf16 bf16x8 __attribute__((ext_vector_type(8)));
typedef float floatx4 __attribute__((ext_vector_type(4)));

#define GLOBAL_AS __attribute__((address_space(1)))
#define LDS_AS __attribute__((address_space(3)))

__device__ __forceinline__ unsigned short f2bf_rne(float x) {
  unsigned u = __float_as_uint(x);
  u += 0x7FFFu + ((u >> 16) & 1u);
  return (unsigned short)(u >> 16);
}
__device__ __forceinline__ float bf2f(unsigned short b) {
  return __uint_as_float(((unsigned)b) << 16);
}

// ---------------- kernel 1: fp32 -> bf16 convert + row norms + init ----------------
// R10 body (reg-staged, 8 loads in flight; measured neutral vs R5 but theoretically
// sound). Also zeroes the dtw finalize counter (stream-ordered, replay-safe).
__global__ __launch_bounds__(256) void prep_kernel(
    const float* __restrict__ X, unsigned short* __restrict__ Xbf,
    float* __restrict__ sq, unsigned long long* __restrict__ posP,
    unsigned long long* __restrict__ negP, unsigned* __restrict__ cnt) {
  const int w = threadIdx.x >> 6, lane = threadIdx.x & 63;
  const int row = blockIdx.x * 4 + w;
  if (blockIdx.x == 0 && threadIdx.x == 0) *cnt = 0u;
  const float4* xr = (const float4*)(X + (size_t)row * DIM);
  ushort4* br = (ushort4*)(Xbf + (size_t)row * DIM);
  float4 v[8];
#pragma unroll
  for (int i = 0; i < 8; ++i) v[i] = xr[lane + i * 64];   // 8 loads in flight
  float s = 0.f;
  ushort4 o[8];
#pragma unroll
  for (int i = 0; i < 8; ++i) {
    o[i].x = f2bf_rne(v[i].x); o[i].y = f2bf_rne(v[i].y);
    o[i].z = f2bf_rne(v[i].z); o[i].w = f2bf_rne(v[i].w);
    // norm of the ROUNDED values so d2 is consistent with the MFMA dot
    float b0 = bf2f(o[i].x), b1 = bf2f(o[i].y), b2 = bf2f(o[i].z), b3 = bf2f(o[i].w);
    s += b0 * b0 + b1 * b1 + b2 * b2 + b3 * b3;
  }
#pragma unroll
  for (int i = 0; i < 8; ++i) br[lane + i * 64] = o[i];
#pragma unroll
  for (int m = 32; m > 0; m >>= 1) s += __shfl_down(s, m, 64);
  if (lane == 0) {
    sq[row] = s;
    posP[row] = 0ULL;
    negP[row] = ~0ULL;
  }
}

// ---------------- kernel 2: fused Gram GEMM + mining (R2-proven, 77 us) ------------
// 128x64 tiles, 1056 blocks (4.1 queued/CU — cross-block overlap is the proven
// latency-hiding mechanism for the 2-barrier loop), 2 waves per block, each wave
// a 64x64 sub-tile: 16 ds_read_b128 : 32 MFMA per K-step. Deep in-block
// pipelining on this geometry is a proven dead end (R3; m232), and in-kernel
// grid barriers cost 30-350 us (R6/R7/R8). Triangle at 77 us == ~920 TF
// square-equivalent == the m97-structure ceiling. DO NOT TOUCH.
#define BM 128
#define BCN 64           // tile cols
#define BKE 64           // K elems staged per iter (128 B per row)
#define NBLK 1056

__device__ __forceinline__ void async16(const void* g, void* l) {
  __builtin_amdgcn_global_load_lds((GLOBAL_AS unsigned int*)g, (LDS_AS unsigned int*)l,
                                   16, 0, 0);
}

// tile id -> (ry, cx); cum(y) = y*(65-y) tiles precede row-chunk y; XCD swizzle 8x132
__device__ __forceinline__ void tile_decode(int tt, int& ry, int& cx) {
  const int t = (tt & 7) * 132 + (tt >> 3);
  int y = (int)((65.0f - sqrtf((float)(4225 - 4 * t))) * 0.5f);
  while ((y + 1) * (64 - y) <= t) ++y;   // cum(y+1) = (y+1)*(64-y)
  while (y * (65 - y) > t) --y;
  ry = y;
  cx = 2 * y + (t - y * (65 - y));
}

__global__ __launch_bounds__(128, 3) void gemm_mine_kernel(
    const unsigned short* __restrict__ Xbf, const float* __restrict__ sq,
    const int* __restrict__ targets,
    unsigned long long* __restrict__ posP, unsigned long long* __restrict__ negP) {
  int ry, cx;
  tile_decode(blockIdx.x, ry, cx);
  const int r0 = ry * BM;
  const int c0 = cx * BCN;

  __shared__ __align__(16) unsigned short Ab[BM * BKE];   // 16 KB
  __shared__ __align__(16) unsigned short Bb[BCN * BKE];  //  8 KB
  const int tid = threadIdx.x;
  const int lane = tid & 63;
  const int w = tid >> 6;          // wave 0..1: rows w*64..w*64+63, all 64 cols
  const int quad = lane >> 4;
  const int ml = lane & 15;

  floatx4 acc[4][4];
#pragma unroll
  for (int i = 0; i < 4; ++i)
#pragma unroll
    for (int j = 0; j < 4; ++j)
#pragma unroll
      for (int k = 0; k < 4; ++k) acc[i][j][k] = 0.f;

  // staging (verified conflict-free): row = 8 chunks of 16 B; chunk c of row R at
  // slot c ^ (R&7); DMA lane -> (row lane>>3, slot lane&7) so lane fetches global
  // chunk (lane&7)^((lane>>3)&7). Each async16 = 8 rows x 128 B.
  // wave w stages A rows w*64..+63 (8 issues) and B rows w*32..+31 (4 issues).
  const int r_rel = lane >> 3;
  const int c_g = (lane & 7) ^ r_rel;
  const unsigned short* gA = Xbf + (size_t)(r0 + w * 64 + r_rel) * DIM + c_g * 8;
  const unsigned short* gB = Xbf + (size_t)(c0 + w * 32 + r_rel) * DIM + c_g * 8;
  unsigned short* lA = Ab + w * 64 * BKE;
  unsigned short* lB = Bb + w * 32 * BKE;
  const int sx = ml & 7;

  for (int k0 = 0; k0 < DIM; k0 += BKE) {
    __syncthreads();
#pragma unroll
    for (int q = 0; q < 8; ++q)
      async16(gA + (size_t)(q * 8) * DIM + k0, lA + q * 8 * BKE);
#pragma unroll
    for (int q = 0; q < 4; ++q)
      async16(gB + (size_t)(q * 8) * DIM + k0, lB + q * 8 * BKE);
    __syncthreads();   // vmcnt(0) drain
#pragma unroll
    for (int h = 0; h < 2; ++h) {
      const int slot = ((h << 2) + quad) ^ sx;
      bf16x8 af[4], bfr[4];
#pragma unroll
      for (int i = 0; i < 4; ++i)
        af[i] = *(const bf16x8*)(Ab + ((w * 64 + i * 16 + ml) * BKE) + slot * 8);
#pragma unroll
      for (int j = 0; j < 4; ++j)
        bfr[j] = *(const bf16x8*)(Bb + ((j * 16 + ml) * BKE) + slot * 8);
#pragma unroll
      for (int i = 0; i < 4; ++i)
#pragma unroll
        for (int j = 0; j < 4; ++j)
          acc[i][j] = __builtin_amdgcn_mfma_f32_16x16x32_bf16(af[i], bfr[j], acc[i][j], 0, 0, 0);
    }
  }

  // epilogue A: row-direction mining. C/D layout: col = lane&15, row = quad*4+reg.
  const int cl = ml;
#pragma unroll
  for (int i = 0; i < 4; ++i) {
#pragma unroll
    for (int rg = 0; rg < 4; ++rg) {
      const int gr = r0 + w * 64 + i * 16 + quad * 4 + rg;
      const int tgt_r = targets[gr];
      const float sqr = sq[gr];
      unsigned long long pm = 0ULL;
      unsigned long long nm = ~0ULL;
#pragma unroll
      for (int j = 0; j < 4; ++j) {
        const int gc = c0 + j * 16 + cl;
        const float d2 = sqr + sq[gc] - 2.0f * acc[i][j][rg];
        const float dist = sqrtf(fmaxf(d2, 1e-12f));
        const unsigned long long ph = ((unsigned long long)__float_as_uint(dist)) << 32;
        if (targets[gc] == tgt_r) {
          // argmax first-index tiebreak: larger (4095-gc) == smaller gc wins on ties
          unsigned long long cand = ph | (unsigned)(4095 - gc);
          pm = pm > cand ? pm : cand;
        } else {
          unsigned long long cand = ph | (unsigned)gc;
          nm = nm < cand ? nm : cand;
        }
      }
#pragma unroll
      for (int m = 1; m < 16; m <<= 1) {
        unsigned long long pmo = __shfl_xor(pm, m, 64);
        unsigned long long nmo = __shfl_xor(nm, m, 64);
        pm = pm > pmo ? pm : pmo;
        nm = nm < nmo ? nm : nmo;
      }
      if (cl == 0) {
        atomicMax(&posP[gr], pm);
        atomicMin(&negP[gr], nm);
      }
    }
  }

  // epilogue B: transposed mining (only when col-range is outside the row-range;
  // for cx in {2ry, 2ry+1} both orderings already appear in row passes).
  if (cx >= 2 * ry + 2) {
#pragma unroll
    for (int j = 0; j < 4; ++j) {
      const int gc = c0 + j * 16 + cl;
      const int tgt_c = targets[gc];
      const float sqc = sq[gc];
      unsigned long long pm = 0ULL;
      unsigned long long nm = ~0ULL;
#pragma unroll
      for (int i = 0; i < 4; ++i) {
#pragma unroll
        for (int rg = 0; rg < 4; ++rg) {
          const int gr = r0 + w * 64 + i * 16 + quad * 4 + rg;
          const float d2 = sq[gr] + sqc - 2.0f * acc[i][j][rg];
          const float dist = sqrtf(fmaxf(d2, 1e-12f));
          const unsigned long long ph = ((unsigned long long)__float_as_uint(dist)) << 32;
          if (targets[gr] == tgt_c) {
            unsigned long long cand = ph | (unsigned)(4095 - gr);
            pm = pm > cand ? pm : cand;
          } else {
            unsigned long long cand = ph | (unsigned)gr;
            nm = nm < cand ? nm : cand;
          }
        }
      }
#pragma unroll
      for (int m = 16; m < 64; m <<= 1) {
        unsigned long long pmo = __shfl_xor(pm, m, 64);
        unsigned long long nmo = __shfl_xor(nm, m, 64);
        pm = pm > pmo ? pm : pmo;
        nm = nm < nmo ? nm : nmo;
      }
      if (quad == 0) {
        atomicMax(&posP[gc], pm);
        atomicMin(&negP[gc], nm);
      }
    }
  }
}

// ---------------- kernel 3: local DTW + merged finalize ---------------------------
// R11: dtw body is byte-identical to the R5/R10 champion (1024 blocks x 256 thr,
// one anchor per wave, interleaved PN in LDS, no contended atomics in the hot
// path). The ONLY change: the separate finalize kernel is absorbed via the
// R8-proven relaxed-agent cnt pattern — per-block partial stored as one 8-byte
// agent-scope atomic store, vmcnt(0), one relaxed atomicAdd(cnt); the 1024th
// arriver reduces the 8 KB of partials in-block. Saves launch gap #3 + the
// serial 1-block finalize dispatch. This isolates the merge from R9's confound.
__global__ __launch_bounds__(256) void local_dtw_kernel(
    const float* __restrict__ LF, const unsigned long long* __restrict__ posP,
    const unsigned long long* __restrict__ negP,
    unsigned long long* __restrict__ parts, unsigned* __restrict__ cnt,
    float* __restrict__ out) {
  __shared__ float bufA[4][1024];
  __shared__ float bufPN[4][2048];
  __shared__ float dmP[4][64];
  __shared__ float dmN[4][64];
  __shared__ float gterms[4], lterms[4];
  __shared__ unsigned finflag;
  const int w = threadIdx.x >> 6, lane = threadIdx.x & 63;
  const int a = blockIdx.x * 4 + w;
  const unsigned long long pp = posP[a];
  const unsigned long long nn = negP[a];
  const int p_ind = 4095 - (int)(pp & 0xFFFFFFFFULL);
  const int n_ind = (int)(nn & 0xFFFFFFFFULL);
  const float dist_ap = __uint_as_float((unsigned)(pp >> 32));
  const float dist_an = __uint_as_float((unsigned)(nn >> 32));

  const float4* ga = (const float4*)(LF + (size_t)a * 1024);
  const float4* gp = (const float4*)(LF + (size_t)p_ind * 1024);
  const float4* gn = (const float4*)(LF + (size_t)n_ind * 1024);
  float4* la = (float4*)bufA[w];
  float4* lpn = (float4*)bufPN[w];
#pragma unroll
  for (int i = 0; i < 4; ++i) {
    const int idx = lane + i * 64;
    la[idx] = ga[idx];
    float4 p = gp[idx];
    float4 n = gn[idx];
    // element e=idx*4+k of P goes to pn[2e], of N to pn[2e+1]
    lpn[2 * idx] = make_float4(p.x, n.x, p.y, n.y);
    lpn[2 * idx + 1] = make_float4(p.z, n.z, p.w, n.w);
  }
  __syncthreads();
  const int t1 = lane >> 3, t2 = lane & 7;
  float sp = 0.f, sn = 0.f;
#pragma unroll 8
  for (int d = 0; d < 128; ++d) {
    float xa = bufA[w][d * 8 + t1];
    float2 pnv = *(const float2*)&bufPN[w][2 * (d * 8 + t2)];
    float e1 = xa - pnv.x; sp += e1 * e1;
    float e2 = xa - pnv.y; sn += e2 * e2;
  }
  dmP[w][lane] = tanhf(0.5f * sqrtf(fmaxf(sp, 1e-12f)));  // == (e^d-1)/(e^d+1)
  dmN[w][lane] = tanhf(0.5f * sqrtf(fmaxf(sn, 1e-12f)));
  __syncthreads();
  // two serial 8x8 DPs per wave run concurrently on lanes 0 and 1
  if (lane < 2) {
    const float* dm = (lane == 0) ? dmP[w] : dmN[w];
    float row[8];
    row[0] = dm[0];
#pragma unroll
    for (int j = 1; j < 8; ++j) row[j] = row[j - 1] + dm[j];
#pragma unroll
    for (int i = 1; i < 8; ++i) {
      row[0] = row[0] + dm[i * 8];
#pragma unroll
      for (int j = 1; j < 8; ++j) row[j] = fminf(row[j], row[j - 1]) + dm[i * 8 + j];
    }
    if (lane == 0) dmP[w][0] = row[7];   // reuse LDS slot to pass ap
    else dmN[w][0] = row[7];             // an
  }
  __syncthreads();
  if (lane == 0) {
    gterms[w] = fmaxf(dist_ap - dist_an + MARGINF, 0.f);
    lterms[w] = fmaxf(dmP[w][0] - dmN[w][0] + MARGINF, 0.f);
  }
  __syncthreads();

  // merged finalize: R8-proven cnt pattern, relaxed agent-scope atomics.
  if (threadIdx.x == 0) {
    float2 v = make_float2(gterms[0] + gterms[1] + gterms[2] + gterms[3],
                           lterms[0] + lterms[1] + lterms[2] + lterms[3]);
    unsigned long long pb;
    __builtin_memcpy(&pb, &v, 8);
    __hip_atomic_store(&parts[blockIdx.x], pb, __ATOMIC_RELAXED,
                       __HIP_MEMORY_SCOPE_AGENT);
    asm volatile("s_waitcnt vmcnt(0)" ::: "memory");   // parts store at coherence pt
    const unsigned old = __hip_atomic_fetch_add(cnt, 1u, __ATOMIC_RELAXED,
                                                __HIP_MEMORY_SCOPE_AGENT);
    finflag = (old == 1023u) ? 1u : 0u;
  }
  __syncthreads();
  if (finflag) {
    // last-arriving block: all 1024 parts are at the coherence point. Reduce.
    float g = 0.f, l = 0.f;
#pragma unroll
    for (int i = 0; i < 4; ++i) {
      unsigned long long pb = __hip_atomic_load(
          &parts[threadIdx.x + i * 256], __ATOMIC_RELAXED, __HIP_MEMORY_SCOPE_AGENT);
      float2 v;
      __builtin_memcpy(&v, &pb, 8);
      g += v.x; l += v.y;
    }
#pragma unroll
    for (int m = 32; m > 0; m >>= 1) {
      g += __shfl_down(g, m, 64);
      l += __shfl_down(l, m, 64);
    }
    __syncthreads();
    if (lane == 0) { gterms[w] = g; lterms[w] = l; }
    __syncthreads();
    if (threadIdx.x == 0) {
      out[0] = (gterms[0] + gterms[1] + gterms[2] + gterms[3]) * (1.0f / 4096.0f);
      out[1] = (lterms[0] + lterms[1] + lterms[2] + lterms[3]) * (1.0f / 4096.0f);
    }
  }
}

extern "C" void kernel_launch(void* const* d_in, const int* in_sizes, int n_in,
                              void* d_out, int out_size, void* d_ws, size_t ws_size,
                              hipStream_t stream) {
  const float* X = (const float*)d_in[0];
  const int* targets = (const int*)d_in[1];
  const float* LF = (const float*)d_in[2];
  float* out = (float*)d_out;

  char* ws = (char*)d_ws;
  size_t off = 0;
  unsigned short* Xbf = (unsigned short*)(ws + off); off += (size_t)NS * DIM * 2;  // 16 MB
  float* sq = (float*)(ws + off); off += (size_t)NS * 4;
  off = (off + 255) & ~(size_t)255;
  unsigned long long* posP = (unsigned long long*)(ws + off); off += (size_t)NS * 8;
  unsigned long long* negP = (unsigned long long*)(ws + off); off += (size_t)NS * 8;
  unsigned long long* parts = (unsigned long long*)(ws + off); off += (size_t)1024 * 8;
  unsigned* cnt = (unsigned*)(ws + off); off += 128;

  prep_kernel<<<NS / 4, 256, 0, stream>>>(X, Xbf, sq, posP, negP, cnt);
  gemm_mine_kernel<<<NBLK, 128, 0, stream>>>(Xbf, sq, targets, posP, negP);
  local_dtw_kernel<<<NS / 4, 256, 0, stream>>>(LF, posP, negP, parts, cnt, out);
}

// Round 12
// 167.938 us; speedup vs baseline: 1.0407x; 1.0407x over previous
//
#include <hip/hip_runtime.h>
#include <stdint.h>

#define NS 4096
#define DIM 2048
#define MARGINF 0.3f

typedef __bf16 bf16x8 __attribute__((ext_vector_type(8)));
typedef float floatx4 __attribute__((ext_vector_type(4)));

#define GLOBAL_AS __attribute__((address_space(1)))
#define LDS_AS __attribute__((address_space(3)))

__device__ __forceinline__ unsigned short f2bf_rne(float x) {
  unsigned u = __float_as_uint(x);
  u += 0x7FFFu + ((u >> 16) & 1u);
  return (unsigned short)(u >> 16);
}
__device__ __forceinline__ float bf2f(unsigned short b) {
  return __uint_as_float(((unsigned)b) << 16);
}

// ---------------- kernel 1: fp32 -> bf16 convert + row norms + init ----------------
// R10 body (reg-staged, 8 loads in flight). One row per wave, pure-shfl reduction.
__global__ __launch_bounds__(256) void prep_kernel(
    const float* __restrict__ X, unsigned short* __restrict__ Xbf,
    float* __restrict__ sq, unsigned long long* __restrict__ posP,
    unsigned long long* __restrict__ negP) {
  const int w = threadIdx.x >> 6, lane = threadIdx.x & 63;
  const int row = blockIdx.x * 4 + w;
  const float4* xr = (const float4*)(X + (size_t)row * DIM);
  ushort4* br = (ushort4*)(Xbf + (size_t)row * DIM);
  float4 v[8];
#pragma unroll
  for (int i = 0; i < 8; ++i) v[i] = xr[lane + i * 64];   // 8 loads in flight
  float s = 0.f;
  ushort4 o[8];
#pragma unroll
  for (int i = 0; i < 8; ++i) {
    o[i].x = f2bf_rne(v[i].x); o[i].y = f2bf_rne(v[i].y);
    o[i].z = f2bf_rne(v[i].z); o[i].w = f2bf_rne(v[i].w);
    // norm of the ROUNDED values so d2 is consistent with the MFMA dot
    float b0 = bf2f(o[i].x), b1 = bf2f(o[i].y), b2 = bf2f(o[i].z), b3 = bf2f(o[i].w);
    s += b0 * b0 + b1 * b1 + b2 * b2 + b3 * b3;
  }
#pragma unroll
  for (int i = 0; i < 8; ++i) br[lane + i * 64] = o[i];
#pragma unroll
  for (int m = 32; m > 0; m >>= 1) s += __shfl_down(s, m, 64);
  if (lane == 0) {
    sq[row] = s;
    posP[row] = 0ULL;
    negP[row] = ~0ULL;
  }
}

// ---------------- kernel 2: fused Gram GEMM + mining (R2-proven, 77 us) ------------
// 128x64 tiles, 1056 blocks (4.1 queued/CU — cross-block overlap is the proven
// latency-hiding mechanism for the 2-barrier loop), 2 waves per block, each wave
// a 64x64 sub-tile: 16 ds_read_b128 : 32 MFMA per K-step. Deep in-block
// pipelining on this geometry is a proven dead end (R3; m232), and in-kernel
// grid barriers cost 6-350 us (R6/R7/R8/R11). Triangle at 77 us == ~920 TF
// square-equivalent == the m97-structure ceiling. DO NOT TOUCH.
#define BM 128
#define BCN 64           // tile cols
#define BKE 64           // K elems staged per iter (128 B per row)
#define NBLK 1056

__device__ __forceinline__ void async16(const void* g, void* l) {
  __builtin_amdgcn_global_load_lds((GLOBAL_AS unsigned int*)g, (LDS_AS unsigned int*)l,
                                   16, 0, 0);
}

// tile id -> (ry, cx); cum(y) = y*(65-y) tiles precede row-chunk y; XCD swizzle 8x132
__device__ __forceinline__ void tile_decode(int tt, int& ry, int& cx) {
  const int t = (tt & 7) * 132 + (tt >> 3);
  int y = (int)((65.0f - sqrtf((float)(4225 - 4 * t))) * 0.5f);
  while ((y + 1) * (64 - y) <= t) ++y;   // cum(y+1) = (y+1)*(64-y)
  while (y * (65 - y) > t) --y;
  ry = y;
  cx = 2 * y + (t - y * (65 - y));
}

__global__ __launch_bounds__(128, 3) void gemm_mine_kernel(
    const unsigned short* __restrict__ Xbf, const float* __restrict__ sq,
    const int* __restrict__ targets,
    unsigned long long* __restrict__ posP, unsigned long long* __restrict__ negP) {
  int ry, cx;
  tile_decode(blockIdx.x, ry, cx);
  const int r0 = ry * BM;
  const int c0 = cx * BCN;

  __shared__ __align__(16) unsigned short Ab[BM * BKE];   // 16 KB
  __shared__ __align__(16) unsigned short Bb[BCN * BKE];  //  8 KB
  const int tid = threadIdx.x;
  const int lane = tid & 63;
  const int w = tid >> 6;          // wave 0..1: rows w*64..w*64+63, all 64 cols
  const int quad = lane >> 4;
  const int ml = lane & 15;

  floatx4 acc[4][4];
#pragma unroll
  for (int i = 0; i < 4; ++i)
#pragma unroll
    for (int j = 0; j < 4; ++j)
#pragma unroll
      for (int k = 0; k < 4; ++k) acc[i][j][k] = 0.f;

  // staging (verified conflict-free): row = 8 chunks of 16 B; chunk c of row R at
  // slot c ^ (R&7); DMA lane -> (row lane>>3, slot lane&7) so lane fetches global
  // chunk (lane&7)^((lane>>3)&7). Each async16 = 8 rows x 128 B.
  // wave w stages A rows w*64..+63 (8 issues) and B rows w*32..+31 (4 issues).
  const int r_rel = lane >> 3;
  const int c_g = (lane & 7) ^ r_rel;
  const unsigned short* gA = Xbf + (size_t)(r0 + w * 64 + r_rel) * DIM + c_g * 8;
  const unsigned short* gB = Xbf + (size_t)(c0 + w * 32 + r_rel) * DIM + c_g * 8;
  unsigned short* lA = Ab + w * 64 * BKE;
  unsigned short* lB = Bb + w * 32 * BKE;
  const int sx = ml & 7;

  for (int k0 = 0; k0 < DIM; k0 += BKE) {
    __syncthreads();
#pragma unroll
    for (int q = 0; q < 8; ++q)
      async16(gA + (size_t)(q * 8) * DIM + k0, lA + q * 8 * BKE);
#pragma unroll
    for (int q = 0; q < 4; ++q)
      async16(gB + (size_t)(q * 8) * DIM + k0, lB + q * 8 * BKE);
    __syncthreads();   // vmcnt(0) drain
#pragma unroll
    for (int h = 0; h < 2; ++h) {
      const int slot = ((h << 2) + quad) ^ sx;
      bf16x8 af[4], bfr[4];
#pragma unroll
      for (int i = 0; i < 4; ++i)
        af[i] = *(const bf16x8*)(Ab + ((w * 64 + i * 16 + ml) * BKE) + slot * 8);
#pragma unroll
      for (int j = 0; j < 4; ++j)
        bfr[j] = *(const bf16x8*)(Bb + ((j * 16 + ml) * BKE) + slot * 8);
#pragma unroll
      for (int i = 0; i < 4; ++i)
#pragma unroll
        for (int j = 0; j < 4; ++j)
          acc[i][j] = __builtin_amdgcn_mfma_f32_16x16x32_bf16(af[i], bfr[j], acc[i][j], 0, 0, 0);
    }
  }

  // epilogue A: row-direction mining. C/D layout: col = lane&15, row = quad*4+reg.
  const int cl = ml;
#pragma unroll
  for (int i = 0; i < 4; ++i) {
#pragma unroll
    for (int rg = 0; rg < 4; ++rg) {
      const int gr = r0 + w * 64 + i * 16 + quad * 4 + rg;
      const int tgt_r = targets[gr];
      const float sqr = sq[gr];
      unsigned long long pm = 0ULL;
      unsigned long long nm = ~0ULL;
#pragma unroll
      for (int j = 0; j < 4; ++j) {
        const int gc = c0 + j * 16 + cl;
        const float d2 = sqr + sq[gc] - 2.0f * acc[i][j][rg];
        const float dist = sqrtf(fmaxf(d2, 1e-12f));
        const unsigned long long ph = ((unsigned long long)__float_as_uint(dist)) << 32;
        if (targets[gc] == tgt_r) {
          // argmax first-index tiebreak: larger (4095-gc) == smaller gc wins on ties
          unsigned long long cand = ph | (unsigned)(4095 - gc);
          pm = pm > cand ? pm : cand;
        } else {
          unsigned long long cand = ph | (unsigned)gc;
          nm = nm < cand ? nm : cand;
        }
      }
#pragma unroll
      for (int m = 1; m < 16; m <<= 1) {
        unsigned long long pmo = __shfl_xor(pm, m, 64);
        unsigned long long nmo = __shfl_xor(nm, m, 64);
        pm = pm > pmo ? pm : pmo;
        nm = nm < nmo ? nm : nmo;
      }
      if (cl == 0) {
        atomicMax(&posP[gr], pm);
        atomicMin(&negP[gr], nm);
      }
    }
  }

  // epilogue B: transposed mining (only when col-range is outside the row-range;
  // for cx in {2ry, 2ry+1} both orderings already appear in row passes).
  if (cx >= 2 * ry + 2) {
#pragma unroll
    for (int j = 0; j < 4; ++j) {
      const int gc = c0 + j * 16 + cl;
      const int tgt_c = targets[gc];
      const float sqc = sq[gc];
      unsigned long long pm = 0ULL;
      unsigned long long nm = ~0ULL;
#pragma unroll
      for (int i = 0; i < 4; ++i) {
#pragma unroll
        for (int rg = 0; rg < 4; ++rg) {
          const int gr = r0 + w * 64 + i * 16 + quad * 4 + rg;
          const float d2 = sq[gr] + sqc - 2.0f * acc[i][j][rg];
          const float dist = sqrtf(fmaxf(d2, 1e-12f));
          const unsigned long long ph = ((unsigned long long)__float_as_uint(dist)) << 32;
          if (targets[gr] == tgt_c) {
            unsigned long long cand = ph | (unsigned)(4095 - gr);
            pm = pm > cand ? pm : cand;
          } else {
            unsigned long long cand = ph | (unsigned)gr;
            nm = nm < cand ? nm : cand;
          }
        }
      }
#pragma unroll
      for (int m = 16; m < 64; m <<= 1) {
        unsigned long long pmo = __shfl_xor(pm, m, 64);
        unsigned long long nmo = __shfl_xor(nm, m, 64);
        pm = pm > pmo ? pm : pmo;
        nm = nm < nmo ? nm : nmo;
      }
      if (quad == 0) {
        atomicMax(&posP[gc], pm);
        atomicMin(&negP[gc], nm);
      }
    }
  }
}

// ---------------- kernel 3: local DTW distances -> per-block partial sums ----------
// R12: champion body with P/N stored in LDS as BF16 (f2bf_rne at staging).
// Mechanism: (1) block LDS 50.2 -> 34.3 KB => 4 blocks/CU, so all 1024 blocks are
// resident in ONE round (was 3/CU -> a straggler round + tail) and 16 waves/CU
// hide the gathers; (2) hot loop reads b32+b32 instead of b32+b64; (3) staging
// PN writes halve (one b128 per float4-pair). A and all distance math stay fp32;
// bf16 rounding of P/N perturbs the local loss by ~1e-3 << 8.4e-2 threshold.
__global__ __launch_bounds__(256) void local_dtw_kernel(
    const float* __restrict__ LF, const unsigned long long* __restrict__ posP,
    const unsigned long long* __restrict__ negP, float2* __restrict__ parts) {
  __shared__ float bufA[4][1024];                 // 16 KB
  __shared__ __align__(16) unsigned short bufPN[4][2048];   // 8 KB (bf16)
  __shared__ float dmP[4][64];
  __shared__ float dmN[4][64];
  __shared__ float gterms[4], lterms[4];
  const int w = threadIdx.x >> 6, lane = threadIdx.x & 63;
  const int a = blockIdx.x * 4 + w;
  const unsigned long long pp = posP[a];
  const unsigned long long nn = negP[a];
  const int p_ind = 4095 - (int)(pp & 0xFFFFFFFFULL);
  const int n_ind = (int)(nn & 0xFFFFFFFFULL);
  const float dist_ap = __uint_as_float((unsigned)(pp >> 32));
  const float dist_an = __uint_as_float((unsigned)(nn >> 32));

  const float4* ga = (const float4*)(LF + (size_t)a * 1024);
  const float4* gp = (const float4*)(LF + (size_t)p_ind * 1024);
  const float4* gn = (const float4*)(LF + (size_t)n_ind * 1024);
  float4* la = (float4*)bufA[w];
  uint4* lpn = (uint4*)bufPN[w];
#pragma unroll
  for (int i = 0; i < 4; ++i) {
    const int idx = lane + i * 64;
    la[idx] = ga[idx];
    float4 p = gp[idx];
    float4 n = gn[idx];
    // element e=idx*4+k of P goes to u16 slot 2e, of N to 2e+1 (same layout as the
    // fp32 champion, half the bytes): one 16-B store covers the float4-pair.
    uint4 pk;
    pk.x = (unsigned)f2bf_rne(p.x) | ((unsigned)f2bf_rne(n.x) << 16);
    pk.y = (unsigned)f2bf_rne(p.y) | ((unsigned)f2bf_rne(n.y) << 16);
    pk.z = (unsigned)f2bf_rne(p.z) | ((unsigned)f2bf_rne(n.z) << 16);
    pk.w = (unsigned)f2bf_rne(p.w) | ((unsigned)f2bf_rne(n.w) << 16);
    lpn[idx] = pk;
  }
  __syncthreads();
  const int t1 = lane >> 3, t2 = lane & 7;
  float sp = 0.f, sn = 0.f;
#pragma unroll 8
  for (int d = 0; d < 128; ++d) {
    float xa = bufA[w][d * 8 + t1];
    const unsigned pnu = *(const unsigned*)&bufPN[w][2 * (d * 8 + t2)];
    float xp = bf2f((unsigned short)(pnu & 0xFFFFu));
    float xn = bf2f((unsigned short)(pnu >> 16));
    float e1 = xa - xp; sp += e1 * e1;
    float e2 = xa - xn; sn += e2 * e2;
  }
  dmP[w][lane] = tanhf(0.5f * sqrtf(fmaxf(sp, 1e-12f)));  // == (e^d-1)/(e^d+1)
  dmN[w][lane] = tanhf(0.5f * sqrtf(fmaxf(sn, 1e-12f)));
  __syncthreads();
  // two serial 8x8 DPs per wave run concurrently on lanes 0 and 1
  if (lane < 2) {
    const float* dm = (lane == 0) ? dmP[w] : dmN[w];
    float row[8];
    row[0] = dm[0];
#pragma unroll
    for (int j = 1; j < 8; ++j) row[j] = row[j - 1] + dm[j];
#pragma unroll
    for (int i = 1; i < 8; ++i) {
      row[0] = row[0] + dm[i * 8];
#pragma unroll
      for (int j = 1; j < 8; ++j) row[j] = fminf(row[j], row[j - 1]) + dm[i * 8 + j];
    }
    if (lane == 0) dmP[w][0] = row[7];   // reuse LDS slot to pass ap
    else dmN[w][0] = row[7];             // an
  }
  __syncthreads();
  if (lane == 0) {
    gterms[w] = fmaxf(dist_ap - dist_an + MARGINF, 0.f);
    lterms[w] = fmaxf(dmP[w][0] - dmN[w][0] + MARGINF, 0.f);
  }
  __syncthreads();
  if (threadIdx.x == 0) {
    parts[blockIdx.x] = make_float2(gterms[0] + gterms[1] + gterms[2] + gterms[3],
                                    lterms[0] + lterms[1] + lterms[2] + lterms[3]);
  }
}

// ---------------- kernel 4: finalize — reduce 1024 partials, write out -------------
// Separate kernel on purpose: merged-cnt variants measured +6..16 us (R9/R11).
__global__ __launch_bounds__(256) void finalize_kernel(
    const float2* __restrict__ parts, float* __restrict__ out) {
  const int t = threadIdx.x;
  float g = 0.f, l = 0.f;
#pragma unroll
  for (int i = 0; i < 4; ++i) {
    float2 v = parts[t + i * 256];
    g += v.x; l += v.y;
  }
#pragma unroll
  for (int m = 32; m > 0; m >>= 1) {
    g += __shfl_down(g, m, 64);
    l += __shfl_down(l, m, 64);
  }
  __shared__ float sg[4], sl[4];
  if ((t & 63) == 0) { sg[t >> 6] = g; sl[t >> 6] = l; }
  __syncthreads();
  if (t == 0) {
    out[0] = (sg[0] + sg[1] + sg[2] + sg[3]) * (1.0f / 4096.0f);
    out[1] = (sl[0] + sl[1] + sl[2] + sl[3]) * (1.0f / 4096.0f);
  }
}

extern "C" void kernel_launch(void* const* d_in, const int* in_sizes, int n_in,
                              void* d_out, int out_size, void* d_ws, size_t ws_size,
                              hipStream_t stream) {
  const float* X = (const float*)d_in[0];
  const int* targets = (const int*)d_in[1];
  const float* LF = (const float*)d_in[2];
  float* out = (float*)d_out;

  char* ws = (char*)d_ws;
  size_t off = 0;
  unsigned short* Xbf = (unsigned short*)(ws + off); off += (size_t)NS * DIM * 2;  // 16 MB
  float* sq = (float*)(ws + off); off += (size_t)NS * 4;
  off = (off + 255) & ~(size_t)255;
  unsigned long long* posP = (unsigned long long*)(ws + off); off += (size_t)NS * 8;
  unsigned long long* negP = (unsigned long long*)(ws + off); off += (size_t)NS * 8;
  float2* parts = (float2*)(ws + off); off += (size_t)1024 * 8;

  prep_kernel<<<NS / 4, 256, 0, stream>>>(X, Xbf, sq, posP, negP);
  gemm_mine_kernel<<<NBLK, 128, 0, stream>>>(Xbf, sq, targets, posP, negP);
  local_dtw_kernel<<<NS / 4, 256, 0, stream>>>(LF, posP, negP, parts);
  finalize_kernel<<<1, 256, 0, stream>>>(parts, out);
}

// Round 13
// 166.281 us; speedup vs baseline: 1.0510x; 1.0100x over previous
//
#include <hip/hip_runtime.h>
#include <stdint.h>

#define NS 4096
#define DIM 2048
#define MARGINF 0.3f

typedef __bf16 bf16x8 __attribute__((ext_vector_type(8)));
typedef float floatx4 __attribute__((ext_vector_type(4)));

#define GLOBAL_AS __attribute__((address_space(1)))
#define LDS_AS __attribute__((address_space(3)))

__device__ __forceinline__ unsigned short f2bf_rne(float x) {
  unsigned u = __float_as_uint(x);
  u += 0x7FFFu + ((u >> 16) & 1u);
  return (unsigned short)(u >> 16);
}
__device__ __forceinline__ float bf2f(unsigned short b) {
  return __uint_as_float(((unsigned)b) << 16);
}

// ---------------- kernel 1: fp32 -> bf16 convert + row norms + init ----------------
// R13: contiguous 32-B span per lane (two adjacent float4s) -> ONE 16-B uint4
// store of 8 packed bf16 per pair. Halves store instructions and doubles per-wave
// write coverage (1 KB/instr) vs the ushort4 (8 B) stores that were common to all
// three earlier prep variants (each measured ~invariant at ~4x the 48 MB roofline).
// Loads stay reg-staged (8 in flight). One row per wave, pure-shfl reduction.
__global__ __launch_bounds__(256) void prep_kernel(
    const float* __restrict__ X, unsigned short* __restrict__ Xbf,
    float* __restrict__ sq, unsigned long long* __restrict__ posP,
    unsigned long long* __restrict__ negP) {
  const int w = threadIdx.x >> 6, lane = threadIdx.x & 63;
  const int row = blockIdx.x * 4 + w;
  const float4* xr = (const float4*)(X + (size_t)row * DIM);
  uint4* br = (uint4*)(Xbf + (size_t)row * DIM);
  // lane owns elems [lane*8 .. lane*8+7] + [512*i ..] : 4 iterations of 8 elems.
  float4 v[8];
#pragma unroll
  for (int i = 0; i < 4; ++i) {
    v[2 * i] = xr[2 * lane + i * 128];       // 8 loads issued up-front,
    v[2 * i + 1] = xr[2 * lane + 1 + i * 128];  // all in flight
  }
  float s = 0.f;
#pragma unroll
  for (int i = 0; i < 4; ++i) {
    const float4 a = v[2 * i], b = v[2 * i + 1];
    unsigned short c0 = f2bf_rne(a.x), c1 = f2bf_rne(a.y), c2 = f2bf_rne(a.z),
                   c3 = f2bf_rne(a.w), c4 = f2bf_rne(b.x), c5 = f2bf_rne(b.y),
                   c6 = f2bf_rne(b.z), c7 = f2bf_rne(b.w);
    // norm of the ROUNDED values so d2 is consistent with the MFMA dot
    float f0 = bf2f(c0), f1 = bf2f(c1), f2 = bf2f(c2), f3 = bf2f(c3);
    float f4 = bf2f(c4), f5 = bf2f(c5), f6 = bf2f(c6), f7 = bf2f(c7);
    s += f0 * f0 + f1 * f1 + f2 * f2 + f3 * f3 + f4 * f4 + f5 * f5 + f6 * f6 + f7 * f7;
    uint4 pk;
    pk.x = (unsigned)c0 | ((unsigned)c1 << 16);
    pk.y = (unsigned)c2 | ((unsigned)c3 << 16);
    pk.z = (unsigned)c4 | ((unsigned)c5 << 16);
    pk.w = (unsigned)c6 | ((unsigned)c7 << 16);
    br[lane + i * 64] = pk;   // 16-B store, 1 KB per wave-instr, coalesced
  }
#pragma unroll
  for (int m = 32; m > 0; m >>= 1) s += __shfl_down(s, m, 64);
  if (lane == 0) {
    sq[row] = s;
    posP[row] = 0ULL;
    negP[row] = ~0ULL;
  }
}

// ---------------- kernel 2: fused Gram GEMM + mining (R2-proven, 77 us) ------------
// 128x64 tiles, 1056 blocks (4.1/CU, all co-resident — cross-block overlap is the
// proven latency-hiding mechanism for the 2-barrier loop), 2 waves per block, each
// wave a 64x64 sub-tile: 16 ds_read_b128 : 32 MFMA per K-step. Deep in-block
// pipelining on this geometry is a proven dead end (R3; m232), in-kernel grid
// barriers cost 6-350 us (R6/R7/R8/R11), and tile reshapes (R1) regress. Triangle
// at 77 us == ~920 TF square-equivalent == the m97-structure ceiling. DO NOT TOUCH.
#define BM 128
#define BCN 64           // tile cols
#define BKE 64           // K elems staged per iter (128 B per row)
#define NBLK 1056

__device__ __forceinline__ void async16(const void* g, void* l) {
  __builtin_amdgcn_global_load_lds((GLOBAL_AS unsigned int*)g, (LDS_AS unsigned int*)l,
                                   16, 0, 0);
}

// tile id -> (ry, cx); cum(y) = y*(65-y) tiles precede row-chunk y; XCD swizzle 8x132
__device__ __forceinline__ void tile_decode(int tt, int& ry, int& cx) {
  const int t = (tt & 7) * 132 + (tt >> 3);
  int y = (int)((65.0f - sqrtf((float)(4225 - 4 * t))) * 0.5f);
  while ((y + 1) * (64 - y) <= t) ++y;   // cum(y+1) = (y+1)*(64-y)
  while (y * (65 - y) > t) --y;
  ry = y;
  cx = 2 * y + (t - y * (65 - y));
}

__global__ __launch_bounds__(128, 3) void gemm_mine_kernel(
    const unsigned short* __restrict__ Xbf, const float* __restrict__ sq,
    const int* __restrict__ targets,
    unsigned long long* __restrict__ posP, unsigned long long* __restrict__ negP) {
  int ry, cx;
  tile_decode(blockIdx.x, ry, cx);
  const int r0 = ry * BM;
  const int c0 = cx * BCN;

  __shared__ __align__(16) unsigned short Ab[BM * BKE];   // 16 KB
  __shared__ __align__(16) unsigned short Bb[BCN * BKE];  //  8 KB
  const int tid = threadIdx.x;
  const int lane = tid & 63;
  const int w = tid >> 6;          // wave 0..1: rows w*64..w*64+63, all 64 cols
  const int quad = lane >> 4;
  const int ml = lane & 15;

  floatx4 acc[4][4];
#pragma unroll
  for (int i = 0; i < 4; ++i)
#pragma unroll
    for (int j = 0; j < 4; ++j)
#pragma unroll
      for (int k = 0; k < 4; ++k) acc[i][j][k] = 0.f;

  // staging (verified conflict-free): row = 8 chunks of 16 B; chunk c of row R at
  // slot c ^ (R&7); DMA lane -> (row lane>>3, slot lane&7) so lane fetches global
  // chunk (lane&7)^((lane>>3)&7). Each async16 = 8 rows x 128 B.
  // wave w stages A rows w*64..+63 (8 issues) and B rows w*32..+31 (4 issues).
  const int r_rel = lane >> 3;
  const int c_g = (lane & 7) ^ r_rel;
  const unsigned short* gA = Xbf + (size_t)(r0 + w * 64 + r_rel) * DIM + c_g * 8;
  const unsigned short* gB = Xbf + (size_t)(c0 + w * 32 + r_rel) * DIM + c_g * 8;
  unsigned short* lA = Ab + w * 64 * BKE;
  unsigned short* lB = Bb + w * 32 * BKE;
  const int sx = ml & 7;

  for (int k0 = 0; k0 < DIM; k0 += BKE) {
    __syncthreads();
#pragma unroll
    for (int q = 0; q < 8; ++q)
      async16(gA + (size_t)(q * 8) * DIM + k0, lA + q * 8 * BKE);
#pragma unroll
    for (int q = 0; q < 4; ++q)
      async16(gB + (size_t)(q * 8) * DIM + k0, lB + q * 8 * BKE);
    __syncthreads();   // vmcnt(0) drain
#pragma unroll
    for (int h = 0; h < 2; ++h) {
      const int slot = ((h << 2) + quad) ^ sx;
      bf16x8 af[4], bfr[4];
#pragma unroll
      for (int i = 0; i < 4; ++i)
        af[i] = *(const bf16x8*)(Ab + ((w * 64 + i * 16 + ml) * BKE) + slot * 8);
#pragma unroll
      for (int j = 0; j < 4; ++j)
        bfr[j] = *(const bf16x8*)(Bb + ((j * 16 + ml) * BKE) + slot * 8);
#pragma unroll
      for (int i = 0; i < 4; ++i)
#pragma unroll
        for (int j = 0; j < 4; ++j)
          acc[i][j] = __builtin_amdgcn_mfma_f32_16x16x32_bf16(af[i], bfr[j], acc[i][j], 0, 0, 0);
    }
  }

  // epilogue A: row-direction mining. C/D layout: col = lane&15, row = quad*4+reg.
  const int cl = ml;
#pragma unroll
  for (int i = 0; i < 4; ++i) {
#pragma unroll
    for (int rg = 0; rg < 4; ++rg) {
      const int gr = r0 + w * 64 + i * 16 + quad * 4 + rg;
      const int tgt_r = targets[gr];
      const float sqr = sq[gr];
      unsigned long long pm = 0ULL;
      unsigned long long nm = ~0ULL;
#pragma unroll
      for (int j = 0; j < 4; ++j) {
        const int gc = c0 + j * 16 + cl;
        const float d2 = sqr + sq[gc] - 2.0f * acc[i][j][rg];
        const float dist = sqrtf(fmaxf(d2, 1e-12f));
        const unsigned long long ph = ((unsigned long long)__float_as_uint(dist)) << 32;
        if (targets[gc] == tgt_r) {
          // argmax first-index tiebreak: larger (4095-gc) == smaller gc wins on ties
          unsigned long long cand = ph | (unsigned)(4095 - gc);
          pm = pm > cand ? pm : cand;
        } else {
          unsigned long long cand = ph | (unsigned)gc;
          nm = nm < cand ? nm : cand;
        }
      }
#pragma unroll
      for (int m = 1; m < 16; m <<= 1) {
        unsigned long long pmo = __shfl_xor(pm, m, 64);
        unsigned long long nmo = __shfl_xor(nm, m, 64);
        pm = pm > pmo ? pm : pmo;
        nm = nm < nmo ? nm : nmo;
      }
      if (cl == 0) {
        atomicMax(&posP[gr], pm);
        atomicMin(&negP[gr], nm);
      }
    }
  }

  // epilogue B: transposed mining (only when col-range is outside the row-range;
  // for cx in {2ry, 2ry+1} both orderings already appear in row passes).
  if (cx >= 2 * ry + 2) {
#pragma unroll
    for (int j = 0; j < 4; ++j) {
      const int gc = c0 + j * 16 + cl;
      const int tgt_c = targets[gc];
      const float sqc = sq[gc];
      unsigned long long pm = 0ULL;
      unsigned long long nm = ~0ULL;
#pragma unroll
      for (int i = 0; i < 4; ++i) {
#pragma unroll
        for (int rg = 0; rg < 4; ++rg) {
          const int gr = r0 + w * 64 + i * 16 + quad * 4 + rg;
          const float d2 = sq[gr] + sqc - 2.0f * acc[i][j][rg];
          const float dist = sqrtf(fmaxf(d2, 1e-12f));
          const unsigned long long ph = ((unsigned long long)__float_as_uint(dist)) << 32;
          if (targets[gr] == tgt_c) {
            unsigned long long cand = ph | (unsigned)(4095 - gr);
            pm = pm > cand ? pm : cand;
          } else {
            unsigned long long cand = ph | (unsigned)gr;
            nm = nm < cand ? nm : cand;
          }
        }
      }
#pragma unroll
      for (int m = 16; m < 64; m <<= 1) {
        unsigned long long pmo = __shfl_xor(pm, m, 64);
        unsigned long long nmo = __shfl_xor(nm, m, 64);
        pm = pm > pmo ? pm : pmo;
        nm = nm < nmo ? nm : nmo;
      }
      if (quad == 0) {
        atomicMax(&posP[gc], pm);
        atomicMin(&negP[gc], nm);
      }
    }
  }
}

// ---------------- kernel 3: local DTW distances -> per-block partial sums ----------
// R12 body (bf16 P/N in LDS: 34.3 KB/block -> 4 blocks/CU, b32+b32 hot loop).
// Measured equal to the fp32 champion; kept for the residency headroom.
__global__ __launch_bounds__(256) void local_dtw_kernel(
    const float* __restrict__ LF, const unsigned long long* __restrict__ posP,
    const unsigned long long* __restrict__ negP, float2* __restrict__ parts) {
  __shared__ float bufA[4][1024];                 // 16 KB
  __shared__ __align__(16) unsigned short bufPN[4][2048];   // 8 KB (bf16)
  __shared__ float dmP[4][64];
  __shared__ float dmN[4][64];
  __shared__ float gterms[4], lterms[4];
  const int w = threadIdx.x >> 6, lane = threadIdx.x & 63;
  const int a = blockIdx.x * 4 + w;
  const unsigned long long pp = posP[a];
  const unsigned long long nn = negP[a];
  const int p_ind = 4095 - (int)(pp & 0xFFFFFFFFULL);
  const int n_ind = (int)(nn & 0xFFFFFFFFULL);
  const float dist_ap = __uint_as_float((unsigned)(pp >> 32));
  const float dist_an = __uint_as_float((unsigned)(nn >> 32));

  const float4* ga = (const float4*)(LF + (size_t)a * 1024);
  const float4* gp = (const float4*)(LF + (size_t)p_ind * 1024);
  const float4* gn = (const float4*)(LF + (size_t)n_ind * 1024);
  float4* la = (float4*)bufA[w];
  uint4* lpn = (uint4*)bufPN[w];
#pragma unroll
  for (int i = 0; i < 4; ++i) {
    const int idx = lane + i * 64;
    la[idx] = ga[idx];
    float4 p = gp[idx];
    float4 n = gn[idx];
    // element e=idx*4+k of P goes to u16 slot 2e, of N to 2e+1.
    uint4 pk;
    pk.x = (unsigned)f2bf_rne(p.x) | ((unsigned)f2bf_rne(n.x) << 16);
    pk.y = (unsigned)f2bf_rne(p.y) | ((unsigned)f2bf_rne(n.y) << 16);
    pk.z = (unsigned)f2bf_rne(p.z) | ((unsigned)f2bf_rne(n.z) << 16);
    pk.w = (unsigned)f2bf_rne(p.w) | ((unsigned)f2bf_rne(n.w) << 16);
    lpn[idx] = pk;
  }
  __syncthreads();
  const int t1 = lane >> 3, t2 = lane & 7;
  float sp = 0.f, sn = 0.f;
#pragma unroll 8
  for (int d = 0; d < 128; ++d) {
    float xa = bufA[w][d * 8 + t1];
    const unsigned pnu = *(const unsigned*)&bufPN[w][2 * (d * 8 + t2)];
    float xp = bf2f((unsigned short)(pnu & 0xFFFFu));
    float xn = bf2f((unsigned short)(pnu >> 16));
    float e1 = xa - xp; sp += e1 * e1;
    float e2 = xa - xn; sn += e2 * e2;
  }
  dmP[w][lane] = tanhf(0.5f * sqrtf(fmaxf(sp, 1e-12f)));  // == (e^d-1)/(e^d+1)
  dmN[w][lane] = tanhf(0.5f * sqrtf(fmaxf(sn, 1e-12f)));
  __syncthreads();
  // two serial 8x8 DPs per wave run concurrently on lanes 0 and 1
  if (lane < 2) {
    const float* dm = (lane == 0) ? dmP[w] : dmN[w];
    float row[8];
    row[0] = dm[0];
#pragma unroll
    for (int j = 1; j < 8; ++j) row[j] = row[j - 1] + dm[j];
#pragma unroll
    for (int i = 1; i < 8; ++i) {
      row[0] = row[0] + dm[i * 8];
#pragma unroll
      for (int j = 1; j < 8; ++j) row[j] = fminf(row[j], row[j - 1]) + dm[i * 8 + j];
    }
    if (lane == 0) dmP[w][0] = row[7];   // reuse LDS slot to pass ap
    else dmN[w][0] = row[7];             // an
  }
  __syncthreads();
  if (lane == 0) {
    gterms[w] = fmaxf(dist_ap - dist_an + MARGINF, 0.f);
    lterms[w] = fmaxf(dmP[w][0] - dmN[w][0] + MARGINF, 0.f);
  }
  __syncthreads();
  if (threadIdx.x == 0) {
    parts[blockIdx.x] = make_float2(gterms[0] + gterms[1] + gterms[2] + gterms[3],
                                    lterms[0] + lterms[1] + lterms[2] + lterms[3]);
  }
}

// ---------------- kernel 4: finalize — reduce 1024 partials, write out -------------
// Separate kernel on purpose: merged-cnt variants measured +6..16 us (R9/R11).
__global__ __launch_bounds__(256) void finalize_kernel(
    const float2* __restrict__ parts, float* __restrict__ out) {
  const int t = threadIdx.x;
  float g = 0.f, l = 0.f;
#pragma unroll
  for (int i = 0; i < 4; ++i) {
    float2 v = parts[t + i * 256];
    g += v.x; l += v.y;
  }
#pragma unroll
  for (int m = 32; m > 0; m >>= 1) {
    g += __shfl_down(g, m, 64);
    l += __shfl_down(l, m, 64);
  }
  __shared__ float sg[4], sl[4];
  if ((t & 63) == 0) { sg[t >> 6] = g; sl[t >> 6] = l; }
  __syncthreads();
  if (t == 0) {
    out[0] = (sg[0] + sg[1] + sg[2] + sg[3]) * (1.0f / 4096.0f);
    out[1] = (sl[0] + sl[1] + sl[2] + sl[3]) * (1.0f / 4096.0f);
  }
}

extern "C" void kernel_launch(void* const* d_in, const int* in_sizes, int n_in,
                              void* d_out, int out_size, void* d_ws, size_t ws_size,
                              hipStream_t stream) {
  const float* X = (const float*)d_in[0];
  const int* targets = (const int*)d_in[1];
  const float* LF = (const float*)d_in[2];
  float* out = (float*)d_out;

  char* ws = (char*)d_ws;
  size_t off = 0;
  unsigned short* Xbf = (unsigned short*)(ws + off); off += (size_t)NS * DIM * 2;  // 16 MB
  float* sq = (float*)(ws + off); off += (size_t)NS * 4;
  off = (off + 255) & ~(size_t)255;
  unsigned long long* posP = (unsigned long long*)(ws + off); off += (size_t)NS * 8;
  unsigned long long* negP = (unsigned long long*)(ws + off); off += (size_t)NS * 8;
  float2* parts = (float2*)(ws + off); off += (size_t)1024 * 8;

  prep_kernel<<<NS / 4, 256, 0, stream>>>(X, Xbf, sq, posP, negP);
  gemm_mine_kernel<<<NBLK, 128, 0, stream>>>(Xbf, sq, targets, posP, negP);
  local_dtw_kernel<<<NS / 4, 256, 0, stream>>>(LF, posP, negP, parts);
  finalize_kernel<<<1, 256, 0, stream>>>(parts, out);
}